// Round 1
// baseline (11642.090 us; speedup 1.0000x reference)
//
#include <hip/hip_runtime.h>
#include <hip/hip_bf16.h>
#include <math.h>

#define TT 4218
#define BB 2
#define DM 768
#define DI 1536
#define DS 16
#define DTR 48
#define LC 64
#define NCHUNK 66
#define ROWS (BB*TT)   // 8436
#define NLAYER 24

typedef short short8 __attribute__((ext_vector_type(8)));
typedef float f32x4 __attribute__((ext_vector_type(4)));

__device__ __forceinline__ float silu_f(float x) { return x / (1.0f + __expf(-x)); }
__device__ __forceinline__ float softplus_f(float x) {
  return (x > 15.0f) ? x : log1pf(__expf(x));
}
__device__ __forceinline__ unsigned short f2bf(float x) {  // RNE
  unsigned int u = __float_as_uint(x);
  u = (u + 0x7fffu + ((u >> 16) & 1u)) >> 16;
  return (unsigned short)u;
}
__device__ __forceinline__ float bf2f(unsigned short s) {
  return __uint_as_float(((unsigned int)s) << 16);
}

// ---------------- fp32 -> bf16 bulk convert ----------------
__global__ __launch_bounds__(256)
void k_f2bf(const float4* __restrict__ in, ushort4* __restrict__ out, int n4) {
  int i = blockIdx.x*256 + threadIdx.x;
  if (i >= n4) return;
  float4 v = in[i];
  ushort4 o;
  o.x = f2bf(v.x); o.y = f2bf(v.y); o.z = f2bf(v.z); o.w = f2bf(v.w);
  out[i] = o;
}

// dt_proj weights: (NL,1536,48) fp32 -> (NL,1536,64) bf16, pad cols 48..63 = 0
__global__ __launch_bounds__(256)
void k_cvt_dtw(const float* __restrict__ in, unsigned short* __restrict__ out, int n) {
  int i = blockIdx.x*256 + threadIdx.x;
  if (i >= n) return;
  int col = i & 63, row = i >> 6;
  out[i] = (col < DTR) ? f2bf(in[row*DTR + col]) : (unsigned short)0;
}

// zero pad cols 48..63 of f_dt (stays zero across all layers within a call)
__global__ __launch_bounds__(256)
void k_zero_dtpad(unsigned short* __restrict__ fdt) {
  int i = blockIdx.x*256 + threadIdx.x;
  if (i >= ROWS*16) return;
  int r = i >> 4, c = i & 15;
  fdt[(size_t)r*64 + DTR + c] = 0;
}

// ---------------- downsample conv: x (B,1,135000) -> h (B,T,768) ----------------
__global__ __launch_bounds__(256)
void k_conv_ds(const float* __restrict__ x, const float* __restrict__ cw,
               const float* __restrict__ cb, float* __restrict__ h) {
  int bt = blockIdx.x;
  int b = bt / TT, t = bt % TT;
  __shared__ float xs[32];
  int tid = threadIdx.x;
  if (tid < 32) xs[tid] = x[(size_t)b*135000 + (size_t)t*32 + tid];
  __syncthreads();
  for (int d = tid; d < DM; d += 256) {
    float s = cb[d];
    const float* w = cw + d*32;
    #pragma unroll
    for (int k = 0; k < 32; ++k) s = fmaf(xs[k], w[k], s);
    h[(size_t)bt*DM + d] = s;
  }
}

// ---------------- RMSNorm over last dim (768), bf16 output ----------------
__global__ __launch_bounds__(256)
void k_rmsnorm(const float* __restrict__ in, const float* __restrict__ w,
               unsigned short* __restrict__ out) {
  int row = blockIdx.x, tid = threadIdx.x;
  const float* xp = in + (size_t)row*DM;
  float v0 = xp[tid], v1 = xp[tid+256], v2 = xp[tid+512];
  float ss = v0*v0 + v1*v1 + v2*v2;
  #pragma unroll
  for (int off = 32; off > 0; off >>= 1) ss += __shfl_down(ss, off, 64);
  __shared__ float sred[4];
  if ((tid & 63) == 0) sred[tid >> 6] = ss;
  __syncthreads();
  float tot = sred[0] + sred[1] + sred[2] + sred[3];
  float sc = rsqrtf(tot * (1.0f/DM) + 1e-5f);
  unsigned short* op = out + (size_t)row*DM;
  op[tid]     = f2bf(v0*sc*w[tid]);
  op[tid+256] = f2bf(v1*sc*w[tid+256]);
  op[tid+512] = f2bf(v2*sc*w[tid+512]);
}

// ---------------- bf16 MFMA GEMM: C[M,N] = A[M,K] * W[N,K]^T ----------------
// 128x128 tile, BK=32, 4 waves of 64x64, 16x16x32 MFMA, global_load_lds staging
// with XOR-swizzled LDS. MODE 0: bf16 split store (u0/z); 1: fp32 accum;
// 2: fp32 store softplus(v + bias[col]).
// Grid.x is padded to 72 (== 0 mod 8): with x-fastest dispatch and flat%8 XCD
// round-robin, each XCD then owns a FIXED set of 9 M-tiles across all N-panels
// (n-outer, m-inner per XCD) -> A-panel (<=1.8MB bf16 K=768) stays L2-resident
// instead of thrashing through L3 24x. Blocks with m0 >= M exit immediately.
#define GLL(g, l) __builtin_amdgcn_global_load_lds( \
    (const __attribute__((address_space(1))) void*)(g), \
    (__attribute__((address_space(3))) void*)(l), 16, 0, 0)

template<int MODE>
__global__ __launch_bounds__(256)
void k_gemm_bf(const unsigned short* __restrict__ A,
               const unsigned short* __restrict__ W,
               const float* __restrict__ bias,
               float* __restrict__ Cf,
               unsigned short* __restrict__ Cb0, unsigned short* __restrict__ Cb1,
               int ldc, int M, int N, int K) {
  const int m0 = blockIdx.x*128, n0 = blockIdx.y*128;
  if (m0 >= M) return;
  __shared__ unsigned short As[128*32];
  __shared__ unsigned short Ws[128*32];
  const int tid = threadIdx.x;
  const int lane = tid & 63;
  const int wave = tid >> 6;
  const int wm = (wave >> 1)*64, wn = (wave & 1)*64;

  const int sA = tid & 3;
  const int r0 = tid >> 2;
  const int r1 = r0 + 64;
  const int seg0 = sA ^ ((r0 >> 1) & 3);
  const int seg1 = sA ^ ((r1 >> 1) & 3);
  const unsigned short* gA0 = A + (size_t)min(m0+r0, M-1)*K + seg0*8;
  const unsigned short* gA1 = A + (size_t)min(m0+r1, M-1)*K + seg1*8;
  const unsigned short* gW0 = W + (size_t)min(n0+r0, N-1)*K + seg0*8;
  const unsigned short* gW1 = W + (size_t)min(n0+r1, N-1)*K + seg1*8;
  unsigned short* lA0 = As + tid*8;
  unsigned short* lA1 = As + (tid+256)*8;
  unsigned short* lW0 = Ws + tid*8;
  unsigned short* lW1 = Ws + (tid+256)*8;

  f32x4 acc[4][4];
  #pragma unroll
  for (int i = 0; i < 4; ++i)
    #pragma unroll
    for (int j = 0; j < 4; ++j) acc[i][j] = (f32x4){0.f,0.f,0.f,0.f};

  const int lr = lane & 15, kg = lane >> 4;
  const int sw = (kg ^ ((lr >> 1) & 3)) * 8;
  const int aoff = (wm + lr)*32 + sw;
  const int boff = (wn + lr)*32 + sw;

  for (int k0 = 0; k0 < K; k0 += 32) {
    GLL(gA0, lA0); GLL(gA1, lA1);
    GLL(gW0, lW0); GLL(gW1, lW1);
    gA0 += 32; gA1 += 32; gW0 += 32; gW1 += 32;
    __syncthreads();
    short8 af[4], bfr[4];
    #pragma unroll
    for (int i = 0; i < 4; ++i) {
      af[i]  = *(const short8*)(As + aoff + i*512);
      bfr[i] = *(const short8*)(Ws + boff + i*512);
    }
    #pragma unroll
    for (int i = 0; i < 4; ++i)
      #pragma unroll
      for (int j = 0; j < 4; ++j)
        acc[i][j] = __builtin_amdgcn_mfma_f32_16x16x32_bf16(af[i], bfr[j], acc[i][j], 0, 0, 0);
    __syncthreads();
  }

  // C/D layout: col=lane&15, row=(lane>>4)*4+reg
  #pragma unroll
  for (int i = 0; i < 4; ++i) {
    int gr0 = m0 + wm + i*16 + kg*4;
    #pragma unroll
    for (int j = 0; j < 4; ++j) {
      int gc = n0 + wn + j*16 + lr;
      if (gc >= N) continue;
      #pragma unroll
      for (int r = 0; r < 4; ++r) {
        int gr = gr0 + r;
        if (gr >= M) continue;
        float v = acc[i][j][r];
        if (MODE == 0) {
          if (gc < DI) Cb0[(size_t)gr*ldc + gc] = f2bf(v);
          else         Cb1[(size_t)gr*ldc + gc - DI] = f2bf(v);
        } else if (MODE == 1) {
          Cf[(size_t)gr*ldc + gc] += v;
        } else {
          Cf[(size_t)gr*ldc + gc] = softplus_f(v + bias[gc]);
        }
      }
    }
  }
}

// ---------------- x_proj GEMM: C[M,80] = A[M,1536] * W[80,1536]^T ----------------
// M-tile 64 (132 blocks), BK=64 (24 staging rounds instead of 48 - this kernel
// runs at ~2 waves/CU so each GLL->vmcnt(0) round is latency-exposed).
// LDS XOR-swizzle: chunk (row r, col-group g) lives at slot g ^ (r & 7).
__global__ __launch_bounds__(256)
void k_gemm_xp(const unsigned short* __restrict__ A,
               const unsigned short* __restrict__ W,
               float* __restrict__ Cpr, unsigned short* __restrict__ Cdt,
               int M) {
  __shared__ unsigned short As[64*64];
  __shared__ unsigned short Ws[80*64];
  const int tid = threadIdx.x;
  const int m0 = blockIdx.x*64;
  const int lane = tid & 63;
  const int wave = tid >> 6;
  const int K = DI;

  // A: 512 16B-chunks (64 rows x 8 col-groups); this thread stages slots tid, tid+256
  const int rA0 = tid >> 3,        gA0s = (tid & 7) ^ (rA0 & 7);
  const int rA1 = (tid+256) >> 3,  gA1s = ((tid+256) & 7) ^ (rA1 & 7);
  const unsigned short* gA0 = A + (size_t)min(m0+rA0, M-1)*K + gA0s*8;
  const unsigned short* gA1 = A + (size_t)min(m0+rA1, M-1)*K + gA1s*8;
  unsigned short* lA0 = As + tid*8;
  unsigned short* lA1 = As + (size_t)(tid+256)*8;
  // W: 640 chunks (80 rows x 8 groups): slots tid, tid+256, tid+512 (waves 0-1)
  const int rW0 = tid >> 3,        gW0s = (tid & 7) ^ (rW0 & 7);
  const int rW1 = (tid+256) >> 3,  gW1s = ((tid+256) & 7) ^ (rW1 & 7);
  const int rW2 = (tid+512) >> 3,  gW2s = ((tid+512) & 7) ^ (rW2 & 7);
  const unsigned short* gW0 = W + (size_t)rW0*K + gW0s*8;
  const unsigned short* gW1 = W + (size_t)rW1*K + gW1s*8;
  const unsigned short* gW2 = W + (size_t)min(rW2,79)*K + gW2s*8;
  unsigned short* lW0 = Ws + tid*8;
  unsigned short* lW1 = Ws + (size_t)(tid+256)*8;
  unsigned short* lW2 = Ws + (size_t)(tid+512)*8;
  const bool doW2 = (tid < 128);  // whole waves 0-1: wave-uniform GLL

  f32x4 acc[5];
  #pragma unroll
  for (int j = 0; j < 5; ++j) acc[j] = (f32x4){0.f,0.f,0.f,0.f};

  const int lr = lane & 15, kg = lane >> 4;
  const int rowA = wave*16 + lr;

  for (int k0 = 0; k0 < K; k0 += 64) {
    GLL(gA0, lA0); GLL(gA1, lA1);
    GLL(gW0, lW0); GLL(gW1, lW1);
    if (doW2) GLL(gW2, lW2);
    gA0 += 64; gA1 += 64; gW0 += 64; gW1 += 64; gW2 += 64;
    __syncthreads();
    #pragma unroll
    for (int ks = 0; ks < 2; ++ks) {
      const int G = ks*4 + kg;
      short8 af = *(const short8*)(As + ((size_t)rowA*8 + (G ^ (rowA & 7)))*8);
      #pragma unroll
      for (int j = 0; j < 5; ++j) {
        const int rw = j*16 + lr;
        short8 bf = *(const short8*)(Ws + ((size_t)rw*8 + (G ^ (rw & 7)))*8);
        acc[j] = __builtin_amdgcn_mfma_f32_16x16x32_bf16(af, bf, acc[j], 0, 0, 0);
      }
    }
    __syncthreads();
  }

  #pragma unroll
  for (int j = 0; j < 5; ++j) {
    int gc = j*16 + lr;
    #pragma unroll
    for (int r = 0; r < 4; ++r) {
      int gr = m0 + wave*16 + kg*4 + r;
      if (gr >= M) continue;
      float v = acc[j][r];
      Cpr[(size_t)gr*80 + gc] = v;
      if (gc < DTR) Cdt[(size_t)gr*64 + gc] = f2bf(v);
    }
  }
}

// ---------------- causal depthwise conv (k=4) + silu; bf16 in/out, 4 d/thread ----
__global__ __launch_bounds__(256)
void k_dwconv(const unsigned short* __restrict__ U0, const float* __restrict__ cw,
              const float* __restrict__ cb, unsigned short* __restrict__ ubf) {
  size_t i4 = (size_t)blockIdx.x*256 + threadIdx.x;
  if (i4 >= (size_t)ROWS*DI/4) return;
  size_t base = i4*4;
  int d = (int)(base % DI);
  size_t bt = base / DI;
  int t = (int)(bt % TT);
  float4 cbv = *(const float4*)(cb + d);
  float s0 = cbv.x, s1 = cbv.y, s2 = cbv.z, s3 = cbv.w;
  float4 w0v = *(const float4*)(cw + (size_t)(d+0)*4);
  float4 w1v = *(const float4*)(cw + (size_t)(d+1)*4);
  float4 w2v = *(const float4*)(cw + (size_t)(d+2)*4);
  float4 w3v = *(const float4*)(cw + (size_t)(d+3)*4);
  const float* w0 = (const float*)&w0v;
  const float* w1 = (const float*)&w1v;
  const float* w2 = (const float*)&w2v;
  const float* w3 = (const float*)&w3v;
  #pragma unroll
  for (int k = 0; k < 4; ++k) {
    int tt = t - 3 + k;
    if (tt < 0) continue;
    ushort4 uu = *(const ushort4*)(U0 + (bt - 3 + k)*DI + d);
    s0 = fmaf(bf2f(uu.x), w0[k], s0);
    s1 = fmaf(bf2f(uu.y), w1[k], s1);
    s2 = fmaf(bf2f(uu.z), w2[k], s2);
    s3 = fmaf(bf2f(uu.w), w3[k], s3);
  }
  ushort4 o4;
  o4.x = f2bf(silu_f(s0)); o4.y = f2bf(silu_f(s1));
  o4.z = f2bf(silu_f(s2)); o4.w = f2bf(silu_f(s3));
  *(ushort4*)(ubf + base) = o4;
}

// ---------------- selective scan, 3-pass chunked linear recurrence ----------------
__global__ __launch_bounds__(256)
void k_scan1(const float* __restrict__ delta, const unsigned short* __restrict__ u,
             const float* __restrict__ proj, const float* __restrict__ A_log,
             float* __restrict__ P, float* __restrict__ H) {
  int c = blockIdx.x, b = blockIdx.z;
  int d = blockIdx.y * 256 + threadIdx.x;
  float A[DS];
  {
    const float4* a4 = (const float4*)(A_log + (size_t)d*DS);
    #pragma unroll
    for (int q = 0; q < 4; ++q) {
      float4 v = a4[q];
      A[q*4+0] = -__expf(v.x); A[q*4+1] = -__expf(v.y);
      A[q*4+2] = -__expf(v.z); A[q*4+3] = -__expf(v.w);
    }
  }
  float h[DS] = {};
  float sdl = 0.0f;   // chunk decay product = exp(A[s] * sum(delta))
  int t0 = c * LC, t1 = min(t0 + LC, TT);
  for (int t = t0; t < t1; ++t) {
    size_t bt = (size_t)b*TT + t;
    float dl = delta[bt*DI + d];
    float du = dl * bf2f(u[bt*DI + d]);
    const float4* pb4 = (const float4*)(proj + bt*80 + DTR);
    float4 B0 = pb4[0], B1 = pb4[1], B2 = pb4[2], B3 = pb4[3];
    float Bv[DS] = {B0.x,B0.y,B0.z,B0.w, B1.x,B1.y,B1.z,B1.w,
                    B2.x,B2.y,B2.z,B2.w, B3.x,B3.y,B3.z,B3.w};
    sdl += dl;
    #pragma unroll
    for (int s = 0; s < DS; ++s) {
      float e = __expf(dl * A[s]);
      h[s] = fmaf(e, h[s], du * Bv[s]);
    }
  }
  size_t o = (((size_t)c*BB + b)*DI + d)*DS;
  #pragma unroll
  for (int q = 0; q < 4; ++q) {
    float4 pv, hv;
    pv.x = __expf(sdl*A[q*4+0]); pv.y = __expf(sdl*A[q*4+1]);
    pv.z = __expf(sdl*A[q*4+2]); pv.w = __expf(sdl*A[q*4+3]);
    hv.x = h[q*4+0]; hv.y = h[q*4+1]; hv.z = h[q*4+2]; hv.w = h[q*4+3];
    *(float4*)(P + o + q*4) = pv;
    *(float4*)(H + o + q*4) = hv;
  }
}

// depth-2 register prefetch: 66-deep dependent chain at <1 block/CU was
// paying full load latency per chunk.
__global__ __launch_bounds__(256)
void k_scan2(float* __restrict__ P, float* __restrict__ H) {
  int i = blockIdx.x*256 + threadIdx.x;
  const size_t CH = (size_t)BB*DI*DS;
  size_t o = (size_t)i;
  float carry = 0.0f;
  float p0 = P[o],      h0 = H[o];
  float p1 = P[o + CH], h1 = H[o + CH];
  for (int c = 0; c < NCHUNK; ++c) {
    float p2 = 0.0f, h2 = 0.0f;
    if (c + 2 < NCHUNK) { size_t o2 = o + 2*CH; p2 = P[o2]; h2 = H[o2]; }
    H[o] = carry;
    carry = fmaf(p0, carry, h0);
    p0 = p1; h0 = h1; p1 = p2; h1 = h2;
    o += CH;
  }
}

__global__ __launch_bounds__(256)
void k_scan3(const float* __restrict__ delta, const unsigned short* __restrict__ u,
             const unsigned short* __restrict__ z, const float* __restrict__ proj,
             const float* __restrict__ A_log, const float* __restrict__ Dskip,
             const float* __restrict__ H, unsigned short* __restrict__ y) {
  int c = blockIdx.x, b = blockIdx.z;
  int d = blockIdx.y * 256 + threadIdx.x;
  float A[DS];
  {
    const float4* a4 = (const float4*)(A_log + (size_t)d*DS);
    #pragma unroll
    for (int q = 0; q < 4; ++q) {
      float4 v = a4[q];
      A[q*4+0] = -__expf(v.x); A[q*4+1] = -__expf(v.y);
      A[q*4+2] = -__expf(v.z); A[q*4+3] = -__expf(v.w);
    }
  }
  float h[DS];
  size_t o = (((size_t)c*BB + b)*DI + d)*DS;
  #pragma unroll
  for (int q = 0; q < 4; ++q) {
    float4 hv = *(const float4*)(H + o + q*4);
    h[q*4+0] = hv.x; h[q*4+1] = hv.y; h[q*4+2] = hv.z; h[q*4+3] = hv.w;
  }
  float Dd = Dskip[d];
  int t0 = c * LC, t1 = min(t0 + LC, TT);
  for (int t = t0; t < t1; ++t) {
    size_t bt = (size_t)b*TT + t;
    float dl = delta[bt*DI + d];
    float uu = bf2f(u[bt*DI + d]);
    float du = dl * uu;
    const float4* pb4 = (const float4*)(proj + bt*80 + DTR);
    float4 B0 = pb4[0], B1 = pb4[1], B2 = pb4[2], B3 = pb4[3];
    float4 C0 = pb4[4], C1 = pb4[5], C2 = pb4[6], C3 = pb4[7];
    float Bv[DS] = {B0.x,B0.y,B0.z,B0.w, B1.x,B1.y,B1.z,B1.w,
                    B2.x,B2.y,B2.z,B2.w, B3.x,B3.y,B3.z,B3.w};
    float Cv[DS] = {C0.x,C0.y,C0.z,C0.w, C1.x,C1.y,C1.z,C1.w,
                    C2.x,C2.y,C2.z,C2.w, C3.x,C3.y,C3.z,C3.w};
    float yt = 0.0f;
    #pragma unroll
    for (int s = 0; s < DS; ++s) {
      float e = __expf(dl * A[s]);
      h[s] = fmaf(e, h[s], du * Bv[s]);
      yt = fmaf(h[s], Cv[s], yt);
    }
    float zz = bf2f(z[bt*DI + d]);
    y[bt*DI + d] = f2bf((yt + uu*Dd) * silu_f(zz));
  }
}

// ---------------- mean-pool partials over T (bf16 input) ----------------
__global__ __launch_bounds__(256)
void k_poolpart(const unsigned short* __restrict__ hn, float* __restrict__ pp) {
  int seg = blockIdx.x, b = blockIdx.z;
  int d = blockIdx.y*256 + threadIdx.x;
  int t0 = seg*132, t1 = min(t0 + 132, TT);
  float s = 0.0f;
  for (int t = t0; t < t1; ++t) s += bf2f(hn[((size_t)b*TT + t)*DM + d]);
  pp[((size_t)b*32 + seg)*DM + d] = s;
}

// ---------------- final head ----------------
__global__ __launch_bounds__(256)
void k_head(const float* __restrict__ pp, const float* __restrict__ pw,
            const float* __restrict__ pb, const float* __restrict__ lnw,
            const float* __restrict__ lnb, float* __restrict__ out) {
  int b = blockIdx.x, tid = threadIdx.x;
  __shared__ float pooled[DM];
  for (int d = tid; d < DM; d += 256) {
    float s = 0.0f;
    for (int seg = 0; seg < 32; ++seg) s += pp[((size_t)b*32 + seg)*DM + d];
    pooled[d] = s * (1.0f/(float)TT);
  }
  __syncthreads();
  __shared__ float zed[64];
  if (tid < 64) {
    float s = pb[tid];
    const float* w = pw + (size_t)tid*DM;
    for (int d = 0; d < DM; ++d) s = fmaf(pooled[d], w[d], s);
    zed[tid] = s;
  }
  __syncthreads();
  __shared__ float mv[2];
  if (tid == 0) {
    float mu = 0.0f;
    for (int l = 0; l < 64; ++l) mu += zed[l];
    mu *= (1.0f/64.0f);
    float var = 0.0f;
    for (int l = 0; l < 64; ++l) { float dd = zed[l]-mu; var += dd*dd; }
    var *= (1.0f/64.0f);
    mv[0] = mu; mv[1] = rsqrtf(var + 1e-5f);
  }
  __syncthreads();
  if (tid < 64) out[b*64 + tid] = (zed[tid]-mv[0])*mv[1]*lnw[tid] + lnb[tid];
}

extern "C" void kernel_launch(void* const* d_in, const int* in_sizes, int n_in,
                              void* d_out, int out_size, void* d_ws, size_t ws_size,
                              hipStream_t stream) {
  (void)in_sizes; (void)n_in; (void)out_size; (void)ws_size;
  const float* x    = (const float*)d_in[0];
  const float* cw   = (const float*)d_in[1];
  const float* cb   = (const float*)d_in[2];
  const float* nw   = (const float*)d_in[3];
  const float* inw  = (const float*)d_in[4];
  const float* c1w  = (const float*)d_in[5];
  const float* c1b  = (const float*)d_in[6];
  const float* xpw  = (const float*)d_in[7];
  const float* dtw  = (const float*)d_in[8];
  const float* dtb  = (const float*)d_in[9];
  const float* alog = (const float*)d_in[10];
  const float* dsk  = (const float*)d_in[11];
  const float* outw = (const float*)d_in[12];
  const float* nfw  = (const float*)d_in[13];
  const float* pw   = (const float*)d_in[14];
  const float* pb   = (const float*)d_in[15];
  const float* lnw  = (const float*)d_in[16];
  const float* lnb  = (const float*)d_in[17];

  char* wsb = (char*)d_ws;
  size_t o = 0;
  float* f_h  = (float*)(wsb + o); o += (size_t)ROWS*DM*4;
  float* f_pr = (float*)(wsb + o); o += (size_t)ROWS*80*4;
  float* f_dl = (float*)(wsb + o); o += (size_t)ROWS*DI*4;
  float* f_P  = (float*)(wsb + o); o += (size_t)NCHUNK*BB*DI*DS*4;
  float* f_H  = (float*)(wsb + o); o += (size_t)NCHUNK*BB*DI*DS*4;
  float* f_pp = (float*)(wsb + o); o += (size_t)BB*32*DM*4;
  unsigned short* hn_bf = (unsigned short*)(wsb + o); o += (size_t)ROWS*DM*2;
  unsigned short* u0_bf = (unsigned short*)(wsb + o); o += (size_t)ROWS*DI*2;
  unsigned short* z_bf  = (unsigned short*)(wsb + o); o += (size_t)ROWS*DI*2;
  unsigned short* u_bf  = (unsigned short*)(wsb + o); o += (size_t)ROWS*DI*2;
  unsigned short* y_bf  = (unsigned short*)(wsb + o); o += (size_t)ROWS*DI*2;
  unsigned short* f_dt  = (unsigned short*)(wsb + o); o += (size_t)ROWS*64*2;
  unsigned short* w_in  = (unsigned short*)(wsb + o); o += (size_t)2*DI*DM*2;
  unsigned short* w_xp  = (unsigned short*)(wsb + o); o += (size_t)NLAYER*80*DI*2;
  unsigned short* w_out = (unsigned short*)(wsb + o); o += (size_t)NLAYER*DM*DI*2;
  unsigned short* w_dt  = (unsigned short*)(wsb + o); o += (size_t)NLAYER*DI*64*2;

  k_conv_ds<<<ROWS, 256, 0, stream>>>(x, cw, cb, f_h);
  // hoisted weight conversions (all layers)
  k_f2bf<<<(NLAYER*80*DI/4+255)/256, 256, 0, stream>>>(
      (const float4*)xpw, (ushort4*)w_xp, NLAYER*80*DI/4);
  k_f2bf<<<(NLAYER*DM*DI/4+255)/256, 256, 0, stream>>>(
      (const float4*)outw, (ushort4*)w_out, NLAYER*DM*DI/4);
  k_cvt_dtw<<<(NLAYER*DI*64+255)/256, 256, 0, stream>>>(dtw, w_dt, NLAYER*DI*64);
  k_zero_dtpad<<<(ROWS*16+255)/256, 256, 0, stream>>>(f_dt);

  for (int lay = 0; lay < NLAYER; ++lay) {
    k_f2bf<<<(2*DI*DM/4+255)/256, 256, 0, stream>>>(
        (const float4*)(inw + (size_t)lay*2*DI*DM), (ushort4*)w_in, 2*DI*DM/4);
    k_rmsnorm<<<ROWS, 256, 0, stream>>>(f_h, nw + (size_t)lay*DM, hn_bf);
    k_gemm_bf<0><<<dim3(72,24), 256, 0, stream>>>(
        hn_bf, w_in, nullptr, nullptr, u0_bf, z_bf, DI, ROWS, 2*DI, DM);
    k_dwconv<<<(int)(((size_t)ROWS*DI/4+255)/256), 256, 0, stream>>>(
        u0_bf, c1w + (size_t)lay*DI*4, c1b + (size_t)lay*DI, u_bf);
    k_gemm_xp<<<132, 256, 0, stream>>>(
        u_bf, w_xp + (size_t)lay*80*DI, f_pr, f_dt, ROWS);
    k_gemm_bf<2><<<dim3(72,12), 256, 0, stream>>>(
        f_dt, w_dt + (size_t)lay*DI*64, dtb + (size_t)lay*DI,
        f_dl, nullptr, nullptr, DI, ROWS, DI, 64);
    k_scan1<<<dim3(NCHUNK,6,BB), 256, 0, stream>>>(
        f_dl, u_bf, f_pr, alog + (size_t)lay*DI*DS, f_P, f_H);
    k_scan2<<<dim3((BB*DI*DS)/256), 256, 0, stream>>>(f_P, f_H);
    k_scan3<<<dim3(NCHUNK,6,BB), 256, 0, stream>>>(
        f_dl, u_bf, z_bf, f_pr, alog + (size_t)lay*DI*DS,
        dsk + (size_t)lay*DI, f_H, y_bf);
    k_gemm_bf<1><<<dim3(72,6), 256, 0, stream>>>(
        y_bf, w_out + (size_t)lay*DM*DI, nullptr,
        f_h, nullptr, nullptr, DM, ROWS, DM, DI);
  }

  k_rmsnorm<<<ROWS, 256, 0, stream>>>(f_h, nfw, hn_bf);
  k_poolpart<<<dim3(32,3,BB), 256, 0, stream>>>(hn_bf, f_pp);
  k_head<<<BB, 256, 0, stream>>>(f_pp, pw, pb, lnw, lnb, (float*)d_out);
}

// Round 2
// 10108.067 us; speedup vs baseline: 1.1518x; 1.1518x over previous
//
#include <hip/hip_runtime.h>
#include <hip/hip_bf16.h>
#include <math.h>

#define TT 4218
#define BB 2
#define DM 768
#define DI 1536
#define DS 16
#define DTR 48
#define LC 64
#define NCHUNK 66
#define ROWS (BB*TT)   // 8436
#define NLAYER 24

typedef short short8 __attribute__((ext_vector_type(8)));
typedef float f32x4 __attribute__((ext_vector_type(4)));

__device__ __forceinline__ float silu_f(float x) { return x / (1.0f + __expf(-x)); }
__device__ __forceinline__ float softplus_f(float x) {
  return (x > 15.0f) ? x : log1pf(__expf(x));
}
__device__ __forceinline__ unsigned short f2bf(float x) {  // RNE
  unsigned int u = __float_as_uint(x);
  u = (u + 0x7fffu + ((u >> 16) & 1u)) >> 16;
  return (unsigned short)u;
}
__device__ __forceinline__ float bf2f(unsigned short s) {
  return __uint_as_float(((unsigned int)s) << 16);
}

// ---------------- fp32 -> bf16 bulk convert ----------------
__global__ __launch_bounds__(256)
void k_f2bf(const float4* __restrict__ in, ushort4* __restrict__ out, int n4) {
  int i = blockIdx.x*256 + threadIdx.x;
  if (i >= n4) return;
  float4 v = in[i];
  ushort4 o;
  o.x = f2bf(v.x); o.y = f2bf(v.y); o.z = f2bf(v.z); o.w = f2bf(v.w);
  out[i] = o;
}

// dt_proj weights: (NL,1536,48) fp32 -> (NL,1536,64) bf16, pad cols 48..63 = 0
__global__ __launch_bounds__(256)
void k_cvt_dtw(const float* __restrict__ in, unsigned short* __restrict__ out, int n) {
  int i = blockIdx.x*256 + threadIdx.x;
  if (i >= n) return;
  int col = i & 63, row = i >> 6;
  out[i] = (col < DTR) ? f2bf(in[row*DTR + col]) : (unsigned short)0;
}

// zero pad cols 48..63 of f_dt (stays zero across all layers within a call)
__global__ __launch_bounds__(256)
void k_zero_dtpad(unsigned short* __restrict__ fdt) {
  int i = blockIdx.x*256 + threadIdx.x;
  if (i >= ROWS*16) return;
  int r = i >> 4, c = i & 15;
  fdt[(size_t)r*64 + DTR + c] = 0;
}

// ---------------- downsample conv: x (B,1,135000) -> h (B,T,768) ----------------
__global__ __launch_bounds__(256)
void k_conv_ds(const float* __restrict__ x, const float* __restrict__ cw,
               const float* __restrict__ cb, float* __restrict__ h) {
  int bt = blockIdx.x;
  int b = bt / TT, t = bt % TT;
  __shared__ float xs[32];
  int tid = threadIdx.x;
  if (tid < 32) xs[tid] = x[(size_t)b*135000 + (size_t)t*32 + tid];
  __syncthreads();
  for (int d = tid; d < DM; d += 256) {
    float s = cb[d];
    const float* w = cw + d*32;
    #pragma unroll
    for (int k = 0; k < 32; ++k) s = fmaf(xs[k], w[k], s);
    h[(size_t)bt*DM + d] = s;
  }
}

// ---------------- RMSNorm over last dim (768), bf16 output ----------------
__global__ __launch_bounds__(256)
void k_rmsnorm(const float* __restrict__ in, const float* __restrict__ w,
               unsigned short* __restrict__ out) {
  int row = blockIdx.x, tid = threadIdx.x;
  const float* xp = in + (size_t)row*DM;
  float v0 = xp[tid], v1 = xp[tid+256], v2 = xp[tid+512];
  float ss = v0*v0 + v1*v1 + v2*v2;
  #pragma unroll
  for (int off = 32; off > 0; off >>= 1) ss += __shfl_down(ss, off, 64);
  __shared__ float sred[4];
  if ((tid & 63) == 0) sred[tid >> 6] = ss;
  __syncthreads();
  float tot = sred[0] + sred[1] + sred[2] + sred[3];
  float sc = rsqrtf(tot * (1.0f/DM) + 1e-5f);
  unsigned short* op = out + (size_t)row*DM;
  op[tid]     = f2bf(v0*sc*w[tid]);
  op[tid+256] = f2bf(v1*sc*w[tid+256]);
  op[tid+512] = f2bf(v2*sc*w[tid+512]);
}

// ---------------- bf16 MFMA GEMM: C[M,N] = A[M,K] * W[N,K]^T ----------------
// 128x128 tile, BK=64 (halves the per-iteration vmcnt(0) drain count vs BK=32;
// 32 MFMA per wave per barrier instead of 16). LDS 2x16KB, ~4 blocks/CU.
// Swizzle: LDS slot (row, g) holds global k-group g ^ (row&7); GLL dest is
// linear, source is pre-swizzled, read applies the same XOR (involution).
// Grid.x padded to 72 (== 0 mod 8): each XCD owns a fixed set of 9 M-tiles
// across all N-panels -> A-panel stays L2-resident.
// MODE 0: bf16 split store (u0/z); 1: fp32 accum; 2: fp32 softplus(v+bias).
#define GLL(g, l) __builtin_amdgcn_global_load_lds( \
    (const __attribute__((address_space(1))) void*)(g), \
    (__attribute__((address_space(3))) void*)(l), 16, 0, 0)

template<int MODE>
__global__ __launch_bounds__(256)
void k_gemm_bf(const unsigned short* __restrict__ A,
               const unsigned short* __restrict__ W,
               const float* __restrict__ bias,
               float* __restrict__ Cf,
               unsigned short* __restrict__ Cb0, unsigned short* __restrict__ Cb1,
               int ldc, int M, int N, int K) {
  const int m0 = blockIdx.x*128, n0 = blockIdx.y*128;
  if (m0 >= M) return;
  __shared__ unsigned short As[128*64];
  __shared__ unsigned short Ws[128*64];
  const int tid = threadIdx.x;
  const int lane = tid & 63;
  const int wave = tid >> 6;
  const int wm = (wave >> 1)*64, wn = (wave & 1)*64;

  // staging: 1024 16B chunks per matrix; thread stages chunks i*256+tid, i=0..3
  const unsigned short* gA[4];
  const unsigned short* gW[4];
  unsigned short* lA[4];
  unsigned short* lW[4];
  #pragma unroll
  for (int i = 0; i < 4; ++i) {
    int c = i*256 + tid;
    int row = c >> 3;
    int gs = (c & 7) ^ (row & 7);
    gA[i] = A + (size_t)min(m0+row, M-1)*K + gs*8;
    gW[i] = W + (size_t)min(n0+row, N-1)*K + gs*8;
    lA[i] = As + (size_t)c*8;
    lW[i] = Ws + (size_t)c*8;
  }

  f32x4 acc[4][4];
  #pragma unroll
  for (int i = 0; i < 4; ++i)
    #pragma unroll
    for (int j = 0; j < 4; ++j) acc[i][j] = (f32x4){0.f,0.f,0.f,0.f};

  const int lr = lane & 15, kg = lane >> 4;

  for (int k0 = 0; k0 < K; k0 += 64) {
    #pragma unroll
    for (int i = 0; i < 4; ++i) GLL(gA[i], lA[i]);
    #pragma unroll
    for (int i = 0; i < 4; ++i) GLL(gW[i], lW[i]);
    #pragma unroll
    for (int i = 0; i < 4; ++i) { gA[i] += 64; gW[i] += 64; }
    __syncthreads();
    #pragma unroll
    for (int kk = 0; kk < 2; ++kk) {
      const int ks = kk*4 + kg;
      short8 af[4], bfr[4];
      #pragma unroll
      for (int i = 0; i < 4; ++i) {
        const int R  = wm + i*16 + lr;
        const int Rw = wn + i*16 + lr;
        af[i]  = *(const short8*)(As + ((size_t)R*8  + (ks ^ (R  & 7)))*8);
        bfr[i] = *(const short8*)(Ws + ((size_t)Rw*8 + (ks ^ (Rw & 7)))*8);
      }
      #pragma unroll
      for (int i = 0; i < 4; ++i)
        #pragma unroll
        for (int j = 0; j < 4; ++j)
          acc[i][j] = __builtin_amdgcn_mfma_f32_16x16x32_bf16(af[i], bfr[j], acc[i][j], 0, 0, 0);
    }
    __syncthreads();
  }

  // C/D layout: col=lane&15, row=(lane>>4)*4+reg
  #pragma unroll
  for (int i = 0; i < 4; ++i) {
    int gr0 = m0 + wm + i*16 + kg*4;
    #pragma unroll
    for (int j = 0; j < 4; ++j) {
      int gc = n0 + wn + j*16 + lr;
      if (gc >= N) continue;
      #pragma unroll
      for (int r = 0; r < 4; ++r) {
        int gr = gr0 + r;
        if (gr >= M) continue;
        float v = acc[i][j][r];
        if (MODE == 0) {
          if (gc < DI) Cb0[(size_t)gr*ldc + gc] = f2bf(v);
          else         Cb1[(size_t)gr*ldc + gc - DI] = f2bf(v);
        } else if (MODE == 1) {
          Cf[(size_t)gr*ldc + gc] += v;
        } else {
          Cf[(size_t)gr*ldc + gc] = softplus_f(v + bias[gc]);
        }
      }
    }
  }
}

// ---------------- x_proj GEMM: C[M,80] = A[M,1536] * W[80,1536]^T ----------------
// M-tile 64 (132 blocks), BK=64. LDS XOR-swizzle slot = g ^ (row&7).
__global__ __launch_bounds__(256)
void k_gemm_xp(const unsigned short* __restrict__ A,
               const unsigned short* __restrict__ W,
               float* __restrict__ Cpr, unsigned short* __restrict__ Cdt,
               int M) {
  __shared__ unsigned short As[64*64];
  __shared__ unsigned short Ws[80*64];
  const int tid = threadIdx.x;
  const int m0 = blockIdx.x*64;
  const int lane = tid & 63;
  const int wave = tid >> 6;
  const int K = DI;

  // A: 512 16B-chunks (64 rows x 8 col-groups); this thread stages slots tid, tid+256
  const int rA0 = tid >> 3,        gA0s = (tid & 7) ^ (rA0 & 7);
  const int rA1 = (tid+256) >> 3,  gA1s = ((tid+256) & 7) ^ (rA1 & 7);
  const unsigned short* gA0 = A + (size_t)min(m0+rA0, M-1)*K + gA0s*8;
  const unsigned short* gA1 = A + (size_t)min(m0+rA1, M-1)*K + gA1s*8;
  unsigned short* lA0 = As + tid*8;
  unsigned short* lA1 = As + (size_t)(tid+256)*8;
  // W: 640 chunks (80 rows x 8 groups): slots tid, tid+256, tid+512 (waves 0-1)
  const int rW0 = tid >> 3,        gW0s = (tid & 7) ^ (rW0 & 7);
  const int rW1 = (tid+256) >> 3,  gW1s = ((tid+256) & 7) ^ (rW1 & 7);
  const int rW2 = (tid+512) >> 3,  gW2s = ((tid+512) & 7) ^ (rW2 & 7);
  const unsigned short* gW0 = W + (size_t)rW0*K + gW0s*8;
  const unsigned short* gW1 = W + (size_t)rW1*K + gW1s*8;
  const unsigned short* gW2 = W + (size_t)min(rW2,79)*K + gW2s*8;
  unsigned short* lW0 = Ws + tid*8;
  unsigned short* lW1 = Ws + (size_t)(tid+256)*8;
  unsigned short* lW2 = Ws + (size_t)(tid+512)*8;
  const bool doW2 = (tid < 128);  // whole waves 0-1: wave-uniform GLL

  f32x4 acc[5];
  #pragma unroll
  for (int j = 0; j < 5; ++j) acc[j] = (f32x4){0.f,0.f,0.f,0.f};

  const int lr = lane & 15, kg = lane >> 4;
  const int rowA = wave*16 + lr;

  for (int k0 = 0; k0 < K; k0 += 64) {
    GLL(gA0, lA0); GLL(gA1, lA1);
    GLL(gW0, lW0); GLL(gW1, lW1);
    if (doW2) GLL(gW2, lW2);
    gA0 += 64; gA1 += 64; gW0 += 64; gW1 += 64; gW2 += 64;
    __syncthreads();
    #pragma unroll
    for (int ks = 0; ks < 2; ++ks) {
      const int G = ks*4 + kg;
      short8 af = *(const short8*)(As + ((size_t)rowA*8 + (G ^ (rowA & 7)))*8);
      #pragma unroll
      for (int j = 0; j < 5; ++j) {
        const int rw = j*16 + lr;
        short8 bf = *(const short8*)(Ws + ((size_t)rw*8 + (G ^ (rw & 7)))*8);
        acc[j] = __builtin_amdgcn_mfma_f32_16x16x32_bf16(af, bf, acc[j], 0, 0, 0);
      }
    }
    __syncthreads();
  }

  #pragma unroll
  for (int j = 0; j < 5; ++j) {
    int gc = j*16 + lr;
    #pragma unroll
    for (int r = 0; r < 4; ++r) {
      int gr = m0 + wave*16 + kg*4 + r;
      if (gr >= M) continue;
      float v = acc[j][r];
      Cpr[(size_t)gr*80 + gc] = v;
      if (gc < DTR) Cdt[(size_t)gr*64 + gc] = f2bf(v);
    }
  }
}

// ---------------- causal depthwise conv (k=4) + silu; bf16 in/out, 4 d/thread ----
__global__ __launch_bounds__(256)
void k_dwconv(const unsigned short* __restrict__ U0, const float* __restrict__ cw,
              const float* __restrict__ cb, unsigned short* __restrict__ ubf) {
  size_t i4 = (size_t)blockIdx.x*256 + threadIdx.x;
  if (i4 >= (size_t)ROWS*DI/4) return;
  size_t base = i4*4;
  int d = (int)(base % DI);
  size_t bt = base / DI;
  int t = (int)(bt % TT);
  float4 cbv = *(const float4*)(cb + d);
  float s0 = cbv.x, s1 = cbv.y, s2 = cbv.z, s3 = cbv.w;
  float4 w0v = *(const float4*)(cw + (size_t)(d+0)*4);
  float4 w1v = *(const float4*)(cw + (size_t)(d+1)*4);
  float4 w2v = *(const float4*)(cw + (size_t)(d+2)*4);
  float4 w3v = *(const float4*)(cw + (size_t)(d+3)*4);
  const float* w0 = (const float*)&w0v;
  const float* w1 = (const float*)&w1v;
  const float* w2 = (const float*)&w2v;
  const float* w3 = (const float*)&w3v;
  #pragma unroll
  for (int k = 0; k < 4; ++k) {
    int tt = t - 3 + k;
    if (tt < 0) continue;
    ushort4 uu = *(const ushort4*)(U0 + (bt - 3 + k)*DI + d);
    s0 = fmaf(bf2f(uu.x), w0[k], s0);
    s1 = fmaf(bf2f(uu.y), w1[k], s1);
    s2 = fmaf(bf2f(uu.z), w2[k], s2);
    s3 = fmaf(bf2f(uu.w), w3[k], s3);
  }
  ushort4 o4;
  o4.x = f2bf(silu_f(s0)); o4.y = f2bf(silu_f(s1));
  o4.z = f2bf(silu_f(s2)); o4.w = f2bf(silu_f(s3));
  *(ushort4*)(ubf + base) = o4;
}

// ---------------- selective scan, 3-pass chunked linear recurrence ----------------
// Pass 1: per-chunk local h and sum(delta) (chunk decay = exp(A*sdl), recomputed
// in pass 2 instead of storing 16 P floats -> 24MB/layer traffic saved).
__global__ __launch_bounds__(256)
void k_scan1(const float* __restrict__ delta, const unsigned short* __restrict__ u,
             const float* __restrict__ proj, const float* __restrict__ A_log,
             float* __restrict__ sdl_out, float* __restrict__ H) {
  int c = blockIdx.x, b = blockIdx.z;
  int d = blockIdx.y * 256 + threadIdx.x;
  float A[DS];
  {
    const float4* a4 = (const float4*)(A_log + (size_t)d*DS);
    #pragma unroll
    for (int q = 0; q < 4; ++q) {
      float4 v = a4[q];
      A[q*4+0] = -__expf(v.x); A[q*4+1] = -__expf(v.y);
      A[q*4+2] = -__expf(v.z); A[q*4+3] = -__expf(v.w);
    }
  }
  float h[DS] = {};
  float sdl = 0.0f;
  int t0 = c * LC, t1 = min(t0 + LC, TT);
  for (int t = t0; t < t1; ++t) {
    size_t bt = (size_t)b*TT + t;
    float dl = delta[bt*DI + d];
    float du = dl * bf2f(u[bt*DI + d]);
    const float4* pb4 = (const float4*)(proj + bt*80 + DTR);
    float4 B0 = pb4[0], B1 = pb4[1], B2 = pb4[2], B3 = pb4[3];
    float Bv[DS] = {B0.x,B0.y,B0.z,B0.w, B1.x,B1.y,B1.z,B1.w,
                    B2.x,B2.y,B2.z,B2.w, B3.x,B3.y,B3.z,B3.w};
    sdl += dl;
    #pragma unroll
    for (int s = 0; s < DS; ++s) {
      float e = __expf(dl * A[s]);
      h[s] = fmaf(e, h[s], du * Bv[s]);
    }
  }
  size_t o = (((size_t)c*BB + b)*DI + d)*DS;
  sdl_out[((size_t)c*BB + b)*DI + d] = sdl;
  #pragma unroll
  for (int q = 0; q < 4; ++q) {
    float4 hv;
    hv.x = h[q*4+0]; hv.y = h[q*4+1]; hv.z = h[q*4+2]; hv.w = h[q*4+3];
    *(float4*)(H + o + q*4) = hv;
  }
}

// Pass 2: 66-deep chain. 64-thread blocks (768 blocks) spread the latency-bound
// chain over all 256 CUs; depth-2 register prefetch.
__global__ __launch_bounds__(64)
void k_scan2(const float* __restrict__ sdl, const float* __restrict__ A_log,
             float* __restrict__ H) {
  int i = blockIdx.x*64 + threadIdx.x;
  int s = i & 15;
  int dd = (i >> 4) % DI;
  int b = i / (DI*DS);
  float As = -__expf(A_log[dd*DS + s]);
  const size_t CH  = (size_t)BB*DI*DS;
  const size_t CHD = (size_t)BB*DI;
  size_t oh = (size_t)i;
  size_t od = (size_t)b*DI + dd;
  float carry = 0.0f;
  float sd0 = sdl[od],       h0 = H[oh];
  float sd1 = sdl[od + CHD], h1 = H[oh + CH];
  for (int c = 0; c < NCHUNK; ++c) {
    float sd2 = 0.0f, h2 = 0.0f;
    if (c + 2 < NCHUNK) { sd2 = sdl[od + 2*CHD]; h2 = H[oh + 2*CH]; }
    H[oh] = carry;
    carry = fmaf(__expf(sd0*As), carry, h0);
    sd0 = sd1; h0 = h1; sd1 = sd2; h1 = h2;
    oh += CH; od += CHD;
  }
}

__global__ __launch_bounds__(256)
void k_scan3(const float* __restrict__ delta, const unsigned short* __restrict__ u,
             const unsigned short* __restrict__ z, const float* __restrict__ proj,
             const float* __restrict__ A_log, const float* __restrict__ Dskip,
             const float* __restrict__ H, unsigned short* __restrict__ y) {
  int c = blockIdx.x, b = blockIdx.z;
  int d = blockIdx.y * 256 + threadIdx.x;
  float A[DS];
  {
    const float4* a4 = (const float4*)(A_log + (size_t)d*DS);
    #pragma unroll
    for (int q = 0; q < 4; ++q) {
      float4 v = a4[q];
      A[q*4+0] = -__expf(v.x); A[q*4+1] = -__expf(v.y);
      A[q*4+2] = -__expf(v.z); A[q*4+3] = -__expf(v.w);
    }
  }
  float h[DS];
  size_t o = (((size_t)c*BB + b)*DI + d)*DS;
  #pragma unroll
  for (int q = 0; q < 4; ++q) {
    float4 hv = *(const float4*)(H + o + q*4);
    h[q*4+0] = hv.x; h[q*4+1] = hv.y; h[q*4+2] = hv.z; h[q*4+3] = hv.w;
  }
  float Dd = Dskip[d];
  int t0 = c * LC, t1 = min(t0 + LC, TT);
  for (int t = t0; t < t1; ++t) {
    size_t bt = (size_t)b*TT + t;
    float dl = delta[bt*DI + d];
    float uu = bf2f(u[bt*DI + d]);
    float du = dl * uu;
    const float4* pb4 = (const float4*)(proj + bt*80 + DTR);
    float4 B0 = pb4[0], B1 = pb4[1], B2 = pb4[2], B3 = pb4[3];
    float4 C0 = pb4[4], C1 = pb4[5], C2 = pb4[6], C3 = pb4[7];
    float Bv[DS] = {B0.x,B0.y,B0.z,B0.w, B1.x,B1.y,B1.z,B1.w,
                    B2.x,B2.y,B2.z,B2.w, B3.x,B3.y,B3.z,B3.w};
    float Cv[DS] = {C0.x,C0.y,C0.z,C0.w, C1.x,C1.y,C1.z,C1.w,
                    C2.x,C2.y,C2.z,C2.w, C3.x,C3.y,C3.z,C3.w};
    float yt = 0.0f;
    #pragma unroll
    for (int s = 0; s < DS; ++s) {
      float e = __expf(dl * A[s]);
      h[s] = fmaf(e, h[s], du * Bv[s]);
      yt = fmaf(h[s], Cv[s], yt);
    }
    float zz = bf2f(z[bt*DI + d]);
    y[bt*DI + d] = f2bf((yt + uu*Dd) * silu_f(zz));
  }
}

// ---------------- mean-pool partials over T (bf16 input) ----------------
__global__ __launch_bounds__(256)
void k_poolpart(const unsigned short* __restrict__ hn, float* __restrict__ pp) {
  int seg = blockIdx.x, b = blockIdx.z;
  int d = blockIdx.y*256 + threadIdx.x;
  int t0 = seg*132, t1 = min(t0 + 132, TT);
  float s = 0.0f;
  for (int t = t0; t < t1; ++t) s += bf2f(hn[((size_t)b*TT + t)*DM + d]);
  pp[((size_t)b*32 + seg)*DM + d] = s;
}

// ---------------- final head ----------------
__global__ __launch_bounds__(256)
void k_head(const float* __restrict__ pp, const float* __restrict__ pw,
            const float* __restrict__ pb, const float* __restrict__ lnw,
            const float* __restrict__ lnb, float* __restrict__ out) {
  int b = blockIdx.x, tid = threadIdx.x;
  __shared__ float pooled[DM];
  for (int d = tid; d < DM; d += 256) {
    float s = 0.0f;
    for (int seg = 0; seg < 32; ++seg) s += pp[((size_t)b*32 + seg)*DM + d];
    pooled[d] = s * (1.0f/(float)TT);
  }
  __syncthreads();
  __shared__ float zed[64];
  if (tid < 64) {
    float s = pb[tid];
    const float* w = pw + (size_t)tid*DM;
    for (int d = 0; d < DM; ++d) s = fmaf(pooled[d], w[d], s);
    zed[tid] = s;
  }
  __syncthreads();
  __shared__ float mv[2];
  if (tid == 0) {
    float mu = 0.0f;
    for (int l = 0; l < 64; ++l) mu += zed[l];
    mu *= (1.0f/64.0f);
    float var = 0.0f;
    for (int l = 0; l < 64; ++l) { float dd = zed[l]-mu; var += dd*dd; }
    var *= (1.0f/64.0f);
    mv[0] = mu; mv[1] = rsqrtf(var + 1e-5f);
  }
  __syncthreads();
  if (tid < 64) out[b*64 + tid] = (zed[tid]-mv[0])*mv[1]*lnw[tid] + lnb[tid];
}

extern "C" void kernel_launch(void* const* d_in, const int* in_sizes, int n_in,
                              void* d_out, int out_size, void* d_ws, size_t ws_size,
                              hipStream_t stream) {
  (void)in_sizes; (void)n_in; (void)out_size;
  const float* x    = (const float*)d_in[0];
  const float* cw   = (const float*)d_in[1];
  const float* cb   = (const float*)d_in[2];
  const float* nw   = (const float*)d_in[3];
  const float* inw  = (const float*)d_in[4];
  const float* c1w  = (const float*)d_in[5];
  const float* c1b  = (const float*)d_in[6];
  const float* xpw  = (const float*)d_in[7];
  const float* dtw  = (const float*)d_in[8];
  const float* dtb  = (const float*)d_in[9];
  const float* alog = (const float*)d_in[10];
  const float* dsk  = (const float*)d_in[11];
  const float* outw = (const float*)d_in[12];
  const float* nfw  = (const float*)d_in[13];
  const float* pw   = (const float*)d_in[14];
  const float* pb   = (const float*)d_in[15];
  const float* lnw  = (const float*)d_in[16];
  const float* lnb  = (const float*)d_in[17];

  char* wsb = (char*)d_ws;
  size_t o = 0;
  float* f_h   = (float*)(wsb + o); o += (size_t)ROWS*DM*4;
  float* f_pr  = (float*)(wsb + o); o += (size_t)ROWS*80*4;
  float* f_dl  = (float*)(wsb + o); o += (size_t)ROWS*DI*4;
  float* f_sdl = (float*)(wsb + o); o += (size_t)NCHUNK*BB*DI*4;
  float* f_H   = (float*)(wsb + o); o += (size_t)NCHUNK*BB*DI*DS*4;
  float* f_pp  = (float*)(wsb + o); o += (size_t)BB*32*DM*4;
  unsigned short* hn_bf = (unsigned short*)(wsb + o); o += (size_t)ROWS*DM*2;
  unsigned short* u0_bf = (unsigned short*)(wsb + o); o += (size_t)ROWS*DI*2;
  unsigned short* z_bf  = (unsigned short*)(wsb + o); o += (size_t)ROWS*DI*2;
  unsigned short* u_bf  = (unsigned short*)(wsb + o); o += (size_t)ROWS*DI*2;
  unsigned short* y_bf  = (unsigned short*)(wsb + o); o += (size_t)ROWS*DI*2;
  unsigned short* f_dt  = (unsigned short*)(wsb + o); o += (size_t)ROWS*64*2;
  unsigned short* w_in  = (unsigned short*)(wsb + o); o += (size_t)2*DI*DM*2;
  unsigned short* w_xp  = (unsigned short*)(wsb + o); o += (size_t)NLAYER*80*DI*2;
  unsigned short* w_out = (unsigned short*)(wsb + o); o += (size_t)NLAYER*DM*DI*2;
  unsigned short* w_dt  = (unsigned short*)(wsb + o); o += (size_t)NLAYER*DI*64*2;
  // all-layer w_in (113MB) only if workspace allows; else per-layer fallback
  size_t w_in_all_sz = (size_t)NLAYER*2*DI*DM*2;
  unsigned short* w_in_all =
      (ws_size >= o + w_in_all_sz) ? (unsigned short*)(wsb + o) : nullptr;

  k_conv_ds<<<ROWS, 256, 0, stream>>>(x, cw, cb, f_h);
  // hoisted weight conversions (all layers)
  k_f2bf<<<(NLAYER*80*DI/4+255)/256, 256, 0, stream>>>(
      (const float4*)xpw, (ushort4*)w_xp, NLAYER*80*DI/4);
  k_f2bf<<<(NLAYER*DM*DI/4+255)/256, 256, 0, stream>>>(
      (const float4*)outw, (ushort4*)w_out, NLAYER*DM*DI/4);
  k_cvt_dtw<<<(NLAYER*DI*64+255)/256, 256, 0, stream>>>(dtw, w_dt, NLAYER*DI*64);
  k_zero_dtpad<<<(ROWS*16+255)/256, 256, 0, stream>>>(f_dt);
  if (w_in_all) {
    int n4 = NLAYER*2*DI*DM/4;
    k_f2bf<<<(n4+255)/256, 256, 0, stream>>>(
        (const float4*)inw, (ushort4*)w_in_all, n4);
  }

  for (int lay = 0; lay < NLAYER; ++lay) {
    const unsigned short* w_in_l;
    if (w_in_all) {
      w_in_l = w_in_all + (size_t)lay*2*DI*DM;
    } else {
      k_f2bf<<<(2*DI*DM/4+255)/256, 256, 0, stream>>>(
          (const float4*)(inw + (size_t)lay*2*DI*DM), (ushort4*)w_in, 2*DI*DM/4);
      w_in_l = w_in;
    }
    k_rmsnorm<<<ROWS, 256, 0, stream>>>(f_h, nw + (size_t)lay*DM, hn_bf);
    k_gemm_bf<0><<<dim3(72,24), 256, 0, stream>>>(
        hn_bf, w_in_l, nullptr, nullptr, u0_bf, z_bf, DI, ROWS, 2*DI, DM);
    k_dwconv<<<(int)(((size_t)ROWS*DI/4+255)/256), 256, 0, stream>>>(
        u0_bf, c1w + (size_t)lay*DI*4, c1b + (size_t)lay*DI, u_bf);
    k_gemm_xp<<<132, 256, 0, stream>>>(
        u_bf, w_xp + (size_t)lay*80*DI, f_pr, f_dt, ROWS);
    k_gemm_bf<2><<<dim3(72,12), 256, 0, stream>>>(
        f_dt, w_dt + (size_t)lay*DI*64, dtb + (size_t)lay*DI,
        f_dl, nullptr, nullptr, DI, ROWS, DI, 64);
    k_scan1<<<dim3(NCHUNK,6,BB), 256, 0, stream>>>(
        f_dl, u_bf, f_pr, alog + (size_t)lay*DI*DS, f_sdl, f_H);
    k_scan2<<<dim3((BB*DI*DS)/64), 64, 0, stream>>>(
        f_sdl, alog + (size_t)lay*DI*DS, f_H);
    k_scan3<<<dim3(NCHUNK,6,BB), 256, 0, stream>>>(
        f_dl, u_bf, z_bf, f_pr, alog + (size_t)lay*DI*DS,
        dsk + (size_t)lay*DI, f_H, y_bf);
    k_gemm_bf<1><<<dim3(72,6), 256, 0, stream>>>(
        y_bf, w_out + (size_t)lay*DM*DI, nullptr,
        f_h, nullptr, nullptr, DM, ROWS, DM, DI);
  }

  k_rmsnorm<<<ROWS, 256, 0, stream>>>(f_h, nfw, hn_bf);
  k_poolpart<<<dim3(32,3,BB), 256, 0, stream>>>(hn_bf, f_pp);
  k_head<<<BB, 256, 0, stream>>>(f_pp, pw, pb, lnw, lnb, (float*)d_out);
}